// Round 1
// baseline (2746.351 us; speedup 1.0000x reference)
//
#include <hip/hip_runtime.h>

#define NB 8
#define NC 512
#define NT 2048
#define ND 256

// workspace layout (float elements)
#define SZ_XPE (8ull*512*2048)            // 8388608
#define OFF_XPE 0ull
#define OFF_M   (OFF_XPE + SZ_XPE)        // 5*512*512 = 1310720
#define OFF_X2  (OFF_M + 5ull*512*512)
#define OFF_G   (OFF_X2 + SZ_XPE)
#define SZ_D    (8ull*256*2048)           // 4194304
#define OFF_TH  (OFF_G + SZ_D)
#define OFF_PH  (OFF_TH + SZ_D)
#define OFF_Y   OFF_XPE                   // xpe dead after k_conv; reuse for y

// ---------------- K1: positional encoding add ----------------
__global__ void k_pe_add(const float* __restrict__ x, float* __restrict__ xpe) {
  int total = NB * NC * NT;
  for (int idx = blockIdx.x * blockDim.x + threadIdx.x; idx < total;
       idx += gridDim.x * blockDim.x) {
    int t = idx % NT;
    int c = (idx / NT) % NC;
    int j2 = c & ~1;  // arange(0,C,2) value for this channel pair
    float dv = __expf(-9.210340371976184f * (float)j2 / (float)NC); // ln(10000)
    float ang = (float)t * dv;
    float pe = (c & 1) ? cosf(ang) : sinf(ang);
    xpe[idx] = x[idx] + pe;
  }
}

// ---------------- K2: merge conv weights through z ----------------
// M[s][o][c], shift = s-2:
//  s=0: Z2*W2_0   s=1: Z1*W1_0   s=2: Z0 + Z1*W1_1 + Z2*W2_1
//  s=3: Z1*W1_2   s=4: Z2*W2_2
// z_w: (512,1536) row-major; tc_w: [m][0][k][c] -> m*1536 + k*512 + c
__global__ __launch_bounds__(256) void k_merge(const float* __restrict__ zw,
                                               const float* __restrict__ w1,
                                               const float* __restrict__ w2,
                                               float* __restrict__ M) {
  int s = blockIdx.z;
  int ob = blockIdx.y * 128 + threadIdx.y * 8;
  int cb = blockIdx.x * 128 + threadIdx.x * 8;
  float acc[8][8];
#pragma unroll
  for (int i = 0; i < 8; ++i)
#pragma unroll
    for (int j = 0; j < 8; ++j) acc[i][j] = 0.f;

  int npass = (s == 2) ? 2 : 1;
  for (int p = 0; p < npass; ++p) {
    int seg, kidx; const float* wsrc;
    if (s == 0)      { seg = 1024; wsrc = w2; kidx = 0; }
    else if (s == 1) { seg = 512;  wsrc = w1; kidx = 0; }
    else if (s == 3) { seg = 512;  wsrc = w1; kidx = 2; }
    else if (s == 4) { seg = 1024; wsrc = w2; kidx = 2; }
    else { if (p == 0) { seg = 512; wsrc = w1; kidx = 1; }
           else        { seg = 1024; wsrc = w2; kidx = 1; } }
    const float* A  = zw + seg;                    // A[o][m], row stride 1536
    const float* Bp = wsrc + (size_t)kidx * 512;   // B[m][c], row stride 1536
    for (int k4 = 0; k4 < 512; k4 += 4) {
      float4 a4[8];
#pragma unroll
      for (int i = 0; i < 8; ++i)
        a4[i] = *(const float4*)(A + (size_t)(ob + i) * 1536 + k4);
#pragma unroll
      for (int kk = 0; kk < 4; ++kk) {
        const float* brow = Bp + (size_t)(k4 + kk) * 1536 + cb;
        float4 b0 = *(const float4*)(brow);
        float4 b1 = *(const float4*)(brow + 4);
#pragma unroll
        for (int i = 0; i < 8; ++i) {
          float av = ((const float*)&a4[i])[kk];
          acc[i][0] += av * b0.x; acc[i][1] += av * b0.y;
          acc[i][2] += av * b0.z; acc[i][3] += av * b0.w;
          acc[i][4] += av * b1.x; acc[i][5] += av * b1.y;
          acc[i][6] += av * b1.z; acc[i][7] += av * b1.w;
        }
      }
    }
  }
  if (s == 2) {
#pragma unroll
    for (int i = 0; i < 8; ++i)
#pragma unroll
      for (int j = 0; j < 8; ++j)
        acc[i][j] += zw[(size_t)(ob + i) * 1536 + cb + j];
  }
  float* dst = M + (size_t)s * 512 * 512;
#pragma unroll
  for (int i = 0; i < 8; ++i)
#pragma unroll
    for (int j = 0; j < 8; ++j)
      dst[(size_t)(ob + i) * 512 + cb + j] = acc[i][j];
}

// ---------------- K3: x2 = sum_s M_s @ shift(xpe, s-2) + z_b ----------------
__global__ __launch_bounds__(256) void k_conv(const float* __restrict__ Mw,
                                              const float* __restrict__ xpe,
                                              const float* __restrict__ zb,
                                              float* __restrict__ x2) {
  int b = blockIdx.z;
  int t0 = blockIdx.x * 128, o0 = blockIdx.y * 128;
  int tid = threadIdx.x;
  int ty = tid >> 4, tx = tid & 15;
  int ob = o0 + ty * 8, tb = t0 + tx * 8;
  __shared__ __align__(16) float bs[16][132];
  float acc[8][8];
#pragma unroll
  for (int i = 0; i < 8; ++i)
#pragma unroll
    for (int j = 0; j < 8; ++j) acc[i][j] = 0.f;
  const float* Xb = xpe + (size_t)b * NC * NT;

  for (int s = 0; s < 5; ++s) {
    const float* A = Mw + (size_t)s * 512 * 512;
    int shift = s - 2;
    for (int k0 = 0; k0 < 512; k0 += 16) {
      __syncthreads();
      {
        int kr = tid >> 4;
        int tq = (tid & 15) * 8;
        const float* src = Xb + (size_t)(k0 + kr) * NT;
#pragma unroll
        for (int j = 0; j < 8; ++j) {
          int tg = t0 + tq + j + shift;
          bs[kr][tq + j] = (tg >= 0 && tg < NT) ? src[tg] : 0.f;
        }
      }
      __syncthreads();
#pragma unroll
      for (int kq = 0; kq < 4; ++kq) {
        float4 a4[8];
#pragma unroll
        for (int i = 0; i < 8; ++i)
          a4[i] = *(const float4*)(A + (size_t)(ob + i) * 512 + k0 + kq * 4);
#pragma unroll
        for (int kk = 0; kk < 4; ++kk) {
          float4 b0 = *(const float4*)&bs[kq * 4 + kk][tx * 8];
          float4 b1 = *(const float4*)&bs[kq * 4 + kk][tx * 8 + 4];
#pragma unroll
          for (int i = 0; i < 8; ++i) {
            float av = ((const float*)&a4[i])[kk];
            acc[i][0] += av * b0.x; acc[i][1] += av * b0.y;
            acc[i][2] += av * b0.z; acc[i][3] += av * b0.w;
            acc[i][4] += av * b1.x; acc[i][5] += av * b1.y;
            acc[i][6] += av * b1.z; acc[i][7] += av * b1.w;
          }
        }
      }
    }
  }
#pragma unroll
  for (int i = 0; i < 8; ++i) {
    float bias = zb[ob + i];
#pragma unroll
    for (int j = 0; j < 8; ++j)
      x2[((size_t)b * NC + ob + i) * NT + tb + j] = acc[i][j] + bias;
  }
}

// ---------------- K4: g/theta/phi projections ----------------
__global__ __launch_bounds__(256) void k_gtp(const float* __restrict__ gw, const float* __restrict__ gbias,
                                             const float* __restrict__ thw, const float* __restrict__ thbias,
                                             const float* __restrict__ phw, const float* __restrict__ phbias,
                                             const float* __restrict__ x2,
                                             float* __restrict__ og, float* __restrict__ oth,
                                             float* __restrict__ oph) {
  int b = blockIdx.z;
  int t0 = blockIdx.x * 128, o0 = blockIdx.y * 128;
  int which = o0 >> 8;
  const float* W; const float* bias; float* out;
  if (which == 0)      { W = gw;  bias = gbias;  out = og;  }
  else if (which == 1) { W = thw; bias = thbias; out = oth; }
  else                 { W = phw; bias = phbias; out = oph; }
  int orel0 = o0 - which * 256;
  int tid = threadIdx.x, ty = tid >> 4, tx = tid & 15;
  int orb = orel0 + ty * 8, tb = t0 + tx * 8;
  const float* Xb = x2 + (size_t)b * NC * NT;
  float acc[8][8];
#pragma unroll
  for (int i = 0; i < 8; ++i)
#pragma unroll
    for (int j = 0; j < 8; ++j) acc[i][j] = 0.f;

  for (int k4 = 0; k4 < 512; k4 += 4) {
    float4 a4[8];
#pragma unroll
    for (int i = 0; i < 8; ++i)
      a4[i] = *(const float4*)(W + (size_t)(orb + i) * 512 + k4);
#pragma unroll
    for (int kk = 0; kk < 4; ++kk) {
      const float* brow = Xb + (size_t)(k4 + kk) * NT + tb;
      float4 b0 = *(const float4*)(brow);
      float4 b1 = *(const float4*)(brow + 4);
#pragma unroll
      for (int i = 0; i < 8; ++i) {
        float av = ((const float*)&a4[i])[kk];
        acc[i][0] += av * b0.x; acc[i][1] += av * b0.y;
        acc[i][2] += av * b0.z; acc[i][3] += av * b0.w;
        acc[i][4] += av * b1.x; acc[i][5] += av * b1.y;
        acc[i][6] += av * b1.z; acc[i][7] += av * b1.w;
      }
    }
  }
  float* Ob = out + (size_t)b * ND * NT;
#pragma unroll
  for (int i = 0; i < 8; ++i) {
    float bi = bias[orb + i];
#pragma unroll
    for (int j = 0; j < 8; ++j)
      Ob[(size_t)(orb + i) * NT + tb + j] = acc[i][j] + bi;
  }
}

// ---------------- K5: flash attention (no scale), y = softmax(th^T phi) g^T ----
__global__ __launch_bounds__(256) void k_attn(const float* __restrict__ th,
                                              const float* __restrict__ ph,
                                              const float* __restrict__ gx,
                                              float* __restrict__ y) {
  int b = blockIdx.y;
  int q0 = blockIdx.x * 32;
  int tid = threadIdx.x;
  int rgrp = tid >> 5, sgrp = tid & 31;
  int r0 = rgrp * 4, s0 = sgrp * 4, dd0 = sgrp * 8;
  __shared__ __align__(16) float q_lds[256][32];
  __shared__ __align__(16) float p_lds[32][132];
  const float* thb = th + (size_t)b * ND * NT;
  const float* phb = ph + (size_t)b * ND * NT;
  const float* gb  = gx + (size_t)b * ND * NT;
  for (int ii = tid; ii < 256 * 32; ii += 256) {
    int d = ii >> 5, r = ii & 31;
    q_lds[d][r] = thb[(size_t)d * NT + q0 + r];
  }
  __syncthreads();
  float m_i[4] = {-3e38f, -3e38f, -3e38f, -3e38f};
  float l_i[4] = {0.f, 0.f, 0.f, 0.f};
  float yacc[4][8];
#pragma unroll
  for (int i = 0; i < 4; ++i)
#pragma unroll
    for (int j = 0; j < 8; ++j) yacc[i][j] = 0.f;

  for (int kt = 0; kt < 16; ++kt) {
    int k0 = kt * 128;
    float sacc[4][4];
#pragma unroll
    for (int i = 0; i < 4; ++i)
#pragma unroll
      for (int j = 0; j < 4; ++j) sacc[i][j] = 0.f;

#pragma unroll 4
    for (int dd = 0; dd < 256; ++dd) {
      float4 kv = *(const float4*)(phb + (size_t)dd * NT + k0 + s0);
      float4 qv = *(const float4*)&q_lds[dd][r0];
      float qa[4] = {qv.x, qv.y, qv.z, qv.w};
      float ka[4] = {kv.x, kv.y, kv.z, kv.w};
#pragma unroll
      for (int i = 0; i < 4; ++i)
#pragma unroll
        for (int j = 0; j < 4; ++j) sacc[i][j] += qa[i] * ka[j];
    }
    // online softmax (rows reduce across the 32 lanes of this half-wave)
#pragma unroll
    for (int i = 0; i < 4; ++i) {
      float rm = fmaxf(fmaxf(sacc[i][0], sacc[i][1]), fmaxf(sacc[i][2], sacc[i][3]));
#pragma unroll
      for (int m = 1; m <= 16; m <<= 1) rm = fmaxf(rm, __shfl_xor(rm, m, 64));
      float mn = fmaxf(m_i[i], rm);
      float al = __expf(m_i[i] - mn);
      m_i[i] = mn;
      float rs = 0.f;
#pragma unroll
      for (int j = 0; j < 4; ++j) { sacc[i][j] = __expf(sacc[i][j] - mn); rs += sacc[i][j]; }
#pragma unroll
      for (int m = 1; m <= 16; m <<= 1) rs += __shfl_xor(rs, m, 64);
      l_i[i] = l_i[i] * al + rs;
#pragma unroll
      for (int j = 0; j < 8; ++j) yacc[i][j] *= al;
      *(float4*)&p_lds[r0 + i][s0] = make_float4(sacc[i][0], sacc[i][1], sacc[i][2], sacc[i][3]);
    }
    __syncthreads();
    // PV: y[r][d] += sum_s P[r][s] * V[s][d];  V[s][d] = g[b][d][k0+s]
    for (int s4 = 0; s4 < 32; ++s4) {
      float4 p4[4];
#pragma unroll
      for (int i = 0; i < 4; ++i) p4[i] = *(const float4*)&p_lds[r0 + i][s4 * 4];
#pragma unroll
      for (int j = 0; j < 8; ++j) {
        float4 vv = *(const float4*)(gb + (size_t)(dd0 + j) * NT + k0 + s4 * 4);
#pragma unroll
        for (int i = 0; i < 4; ++i)
          yacc[i][j] += p4[i].x * vv.x + p4[i].y * vv.y + p4[i].z * vv.z + p4[i].w * vv.w;
      }
    }
    __syncthreads();
  }
  float* yb = y + (size_t)b * ND * NT;
#pragma unroll
  for (int i = 0; i < 4; ++i) {
    float inv = 1.0f / l_i[i];
#pragma unroll
    for (int j = 0; j < 8; ++j)
      yb[(size_t)(dd0 + j) * NT + q0 + r0 + i] = yacc[i][j] * inv;
  }
}

// ---------------- K6: out = BN(W@y + Wb) + x2 ----------------
__global__ __launch_bounds__(256) void k_final(const float* __restrict__ Ww, const float* __restrict__ Wb,
                                               const float* __restrict__ bng, const float* __restrict__ bnb,
                                               const float* __restrict__ bnm, const float* __restrict__ bnv,
                                               const float* __restrict__ y, const float* __restrict__ x2,
                                               float* __restrict__ out) {
  int b = blockIdx.z;
  int t0 = blockIdx.x * 128, o0 = blockIdx.y * 128;
  int tid = threadIdx.x, ty = tid >> 4, tx = tid & 15;
  int ob = o0 + ty * 8, tb = t0 + tx * 8;
  const float* Yb = y + (size_t)b * ND * NT;
  float acc[8][8];
#pragma unroll
  for (int i = 0; i < 8; ++i)
#pragma unroll
    for (int j = 0; j < 8; ++j) acc[i][j] = 0.f;

  for (int k4 = 0; k4 < 256; k4 += 4) {
    float4 a4[8];
#pragma unroll
    for (int i = 0; i < 8; ++i)
      a4[i] = *(const float4*)(Ww + (size_t)(ob + i) * 256 + k4);
#pragma unroll
    for (int kk = 0; kk < 4; ++kk) {
      const float* brow = Yb + (size_t)(k4 + kk) * NT + tb;
      float4 b0 = *(const float4*)(brow);
      float4 b1 = *(const float4*)(brow + 4);
#pragma unroll
      for (int i = 0; i < 8; ++i) {
        float av = ((const float*)&a4[i])[kk];
        acc[i][0] += av * b0.x; acc[i][1] += av * b0.y;
        acc[i][2] += av * b0.z; acc[i][3] += av * b0.w;
        acc[i][4] += av * b1.x; acc[i][5] += av * b1.y;
        acc[i][6] += av * b1.z; acc[i][7] += av * b1.w;
      }
    }
  }
#pragma unroll
  for (int i = 0; i < 8; ++i) {
    int o = ob + i;
    float sc = bng[o] * rsqrtf(bnv[o] + 1e-5f);
    float add = (Wb[o] - bnm[o]) * sc + bnb[o];
#pragma unroll
    for (int j = 0; j < 8; ++j) {
      size_t idx = ((size_t)b * NC + o) * NT + tb + j;
      out[idx] = acc[i][j] * sc + add + x2[idx];
    }
  }
}

extern "C" void kernel_launch(void* const* d_in, const int* in_sizes, int n_in,
                              void* d_out, int out_size, void* d_ws, size_t ws_size,
                              hipStream_t stream) {
  const float* x    = (const float*)d_in[0];
  const float* tcw1 = (const float*)d_in[1];
  const float* tcw2 = (const float*)d_in[2];
  const float* zw   = (const float*)d_in[3];
  const float* zb   = (const float*)d_in[4];
  const float* gw   = (const float*)d_in[5];
  const float* gb   = (const float*)d_in[6];
  const float* thw  = (const float*)d_in[7];
  const float* thb  = (const float*)d_in[8];
  const float* phw  = (const float*)d_in[9];
  const float* phb  = (const float*)d_in[10];
  const float* Ww   = (const float*)d_in[11];
  const float* Wb   = (const float*)d_in[12];
  const float* bng  = (const float*)d_in[13];
  const float* bnb  = (const float*)d_in[14];
  const float* bnm  = (const float*)d_in[15];
  const float* bnv  = (const float*)d_in[16];
  float* ws  = (float*)d_ws;
  float* xpe = ws + OFF_XPE;
  float* Mw  = ws + OFF_M;
  float* x2  = ws + OFF_X2;
  float* og  = ws + OFF_G;
  float* oth = ws + OFF_TH;
  float* oph = ws + OFF_PH;
  float* y   = ws + OFF_Y;  // reuses xpe region (dead after k_conv)

  k_pe_add<<<4096, 256, 0, stream>>>(x, xpe);
  k_merge<<<dim3(4, 4, 5), dim3(16, 16), 0, stream>>>(zw, tcw1, tcw2, Mw);
  k_conv<<<dim3(16, 4, 8), 256, 0, stream>>>(Mw, xpe, zb, x2);
  k_gtp<<<dim3(16, 6, 8), 256, 0, stream>>>(gw, gb, thw, thb, phw, phb, x2, og, oth, oph);
  k_attn<<<dim3(64, 8), 256, 0, stream>>>(oth, oph, og, y);
  k_final<<<dim3(16, 4, 8), 256, 0, stream>>>(Ww, Wb, bng, bnb, bnm, bnv, y, x2, (float*)d_out);
}

// Round 3
// 957.662 us; speedup vs baseline: 2.8678x; 2.8678x over previous
//
#include <hip/hip_runtime.h>
#include <stdint.h>

typedef _Float16 h8v __attribute__((ext_vector_type(8)));
typedef float f4v __attribute__((ext_vector_type(4)));

#define MFMA(a,b,c) __builtin_amdgcn_mfma_f32_16x16x32_f16((a),(b),(c),0,0,0)

__device__ __forceinline__ _Float16 f2h(float f) { return (_Float16)f; }

// ---------------- K1: PE add + transpose:  xpe_t[b][t][c] = f16(x[b][c][t] + pe(t,c))
__global__ __launch_bounds__(256) void k_pe_t(const float* __restrict__ x, _Float16* __restrict__ xpe) {
  __shared__ float tile[32][33];
  int b = blockIdx.z;
  int t0 = blockIdx.x * 32, c0 = blockIdx.y * 32;
  int tid = threadIdx.x;
  int col = tid & 31, rowq = tid >> 5;
#pragma unroll
  for (int i = 0; i < 4; ++i) {
    int c = c0 + rowq + i * 8;
    int t = t0 + col;
    int j2 = c & ~1;
    float dv = expf(-0.01798894603885192f * (float)j2);  // ln(1e4)/512
    float ang = (float)t * dv;
    float pe = (c & 1) ? cosf(ang) : sinf(ang);
    tile[rowq + i * 8][col] = x[((size_t)b * 512 + c) * 2048 + t] + pe;
  }
  __syncthreads();
#pragma unroll
  for (int i = 0; i < 4; ++i) {
    int t = t0 + rowq + i * 8;
    int c = c0 + col;
    xpe[((size_t)b * 2048 + t) * 512 + c] = f2h(tile[col][rowq + i * 8]);
  }
}

// ---------------- K2: cast projection weights to f16 (all four are 131072 elems)
__global__ __launch_bounds__(256) void k_cast(const float* __restrict__ a0, const float* __restrict__ a1,
                                              const float* __restrict__ a2, const float* __restrict__ a3,
                                              _Float16* __restrict__ o) {
  int w = blockIdx.y;
  const float* s = (w == 0) ? a0 : (w == 1) ? a1 : (w == 2) ? a2 : a3;
  int i = blockIdx.x * 256 + threadIdx.x;
  o[(size_t)w * 131072 + i] = f2h(s[i]);
}

// ---------------- K3: merge conv weights through z (fp32 math, f16 out)
__global__ __launch_bounds__(256) void k_merge(const float* __restrict__ zw,
                                               const float* __restrict__ w1,
                                               const float* __restrict__ w2,
                                               _Float16* __restrict__ M) {
  int s = blockIdx.z;
  int ob = blockIdx.y * 128 + threadIdx.y * 8;
  int cb = blockIdx.x * 128 + threadIdx.x * 8;
  float acc[8][8];
#pragma unroll
  for (int i = 0; i < 8; ++i)
#pragma unroll
    for (int j = 0; j < 8; ++j) acc[i][j] = 0.f;

  int npass = (s == 2) ? 2 : 1;
  for (int p = 0; p < npass; ++p) {
    int seg, kidx; const float* wsrc;
    if (s == 0)      { seg = 1024; wsrc = w2; kidx = 0; }
    else if (s == 1) { seg = 512;  wsrc = w1; kidx = 0; }
    else if (s == 3) { seg = 512;  wsrc = w1; kidx = 2; }
    else if (s == 4) { seg = 1024; wsrc = w2; kidx = 2; }
    else { if (p == 0) { seg = 512; wsrc = w1; kidx = 1; }
           else        { seg = 1024; wsrc = w2; kidx = 1; } }
    const float* A  = zw + seg;
    const float* Bp = wsrc + (size_t)kidx * 512;
    for (int k4 = 0; k4 < 512; k4 += 4) {
      float4 a4[8];
#pragma unroll
      for (int i = 0; i < 8; ++i)
        a4[i] = *(const float4*)(A + (size_t)(ob + i) * 1536 + k4);
#pragma unroll
      for (int kk = 0; kk < 4; ++kk) {
        const float* brow = Bp + (size_t)(k4 + kk) * 1536 + cb;
        float4 b0 = *(const float4*)(brow);
        float4 b1 = *(const float4*)(brow + 4);
#pragma unroll
        for (int i = 0; i < 8; ++i) {
          float av = ((const float*)&a4[i])[kk];
          acc[i][0] += av * b0.x; acc[i][1] += av * b0.y;
          acc[i][2] += av * b0.z; acc[i][3] += av * b0.w;
          acc[i][4] += av * b1.x; acc[i][5] += av * b1.y;
          acc[i][6] += av * b1.z; acc[i][7] += av * b1.w;
        }
      }
    }
  }
  if (s == 2) {
#pragma unroll
    for (int i = 0; i < 8; ++i)
#pragma unroll
      for (int j = 0; j < 8; ++j)
        acc[i][j] += zw[(size_t)(ob + i) * 1536 + cb + j];
  }
  _Float16* dst = M + (size_t)s * 512 * 512;
#pragma unroll
  for (int i = 0; i < 8; ++i)
#pragma unroll
    for (int j = 0; j < 8; ++j)
      dst[(size_t)(ob + i) * 512 + cb + j] = f2h(acc[i][j]);
}

// ---------------- shared 64x64-per-wave TN GEMM core (A[M][K], B[N][K], K-contig)
__device__ __forceinline__ void gemm64x64(const _Float16* __restrict__ A, int lda,
                                          const _Float16* __restrict__ B, int ldb,
                                          int K, int lane, f4v acc[4][4]) {
  const int row16 = lane & 15, koff = (lane >> 4) * 8;
  for (int k0 = 0; k0 < K; k0 += 32) {
    h8v a[4], bv[4];
#pragma unroll
    for (int i = 0; i < 4; ++i)
      a[i] = *(const h8v*)(A + (size_t)(i * 16 + row16) * lda + k0 + koff);
#pragma unroll
    for (int i = 0; i < 4; ++i)
      bv[i] = *(const h8v*)(B + (size_t)(i * 16 + row16) * ldb + k0 + koff);
#pragma unroll
    for (int mi = 0; mi < 4; ++mi)
#pragma unroll
      for (int ni = 0; ni < 4; ++ni)
        acc[mi][ni] = MFMA(a[mi], bv[ni], acc[mi][ni]);
  }
}

// ---------------- K4: conv GEMM  x2[o][t] = sum_s M_s[o][:]·xpe[t+s-2][:] + zb
__global__ __launch_bounds__(256) void k_conv(const _Float16* __restrict__ Mh,
                                              const _Float16* __restrict__ xpe,
                                              const float* __restrict__ zb,
                                              float* __restrict__ x2f,
                                              _Float16* __restrict__ x2h) {
  int b = blockIdx.z;
  int o0 = blockIdx.y * 128, t0 = blockIdx.x * 128;
  int wid = threadIdx.x >> 6, lane = threadIdx.x & 63;
  int wm = (wid >> 1) * 64, wn = (wid & 1) * 64;
  int row16 = lane & 15, kg = lane >> 4, koff = kg * 8;
  f4v acc[4][4];
#pragma unroll
  for (int mi = 0; mi < 4; ++mi)
#pragma unroll
    for (int ni = 0; ni < 4; ++ni) acc[mi][ni] = (f4v){0.f, 0.f, 0.f, 0.f};
  const _Float16* Xb = xpe + (size_t)b * 2048 * 512;
  const h8v zerov = {0, 0, 0, 0, 0, 0, 0, 0};

  for (int s = 0; s < 5; ++s) {
    const _Float16* A = Mh + (size_t)s * 512 * 512 + (size_t)(o0 + wm) * 512;
    int shift = s - 2;
    for (int k0 = 0; k0 < 512; k0 += 32) {
      h8v a[4], bv[4];
#pragma unroll
      for (int i = 0; i < 4; ++i)
        a[i] = *(const h8v*)(A + (size_t)(i * 16 + row16) * 512 + k0 + koff);
#pragma unroll
      for (int i = 0; i < 4; ++i) {
        int tr = t0 + wn + i * 16 + row16 + shift;
        bv[i] = (tr >= 0 && tr < 2048) ? *(const h8v*)(Xb + (size_t)tr * 512 + k0 + koff) : zerov;
      }
#pragma unroll
      for (int mi = 0; mi < 4; ++mi)
#pragma unroll
        for (int ni = 0; ni < 4; ++ni)
          acc[mi][ni] = MFMA(a[mi], bv[ni], acc[mi][ni]);
    }
  }
#pragma unroll
  for (int mi = 0; mi < 4; ++mi)
#pragma unroll
    for (int r = 0; r < 4; ++r) {
      int o = o0 + wm + mi * 16 + kg * 4 + r;
      float bias = zb[o];
#pragma unroll
      for (int ni = 0; ni < 4; ++ni) {
        int t = t0 + wn + ni * 16 + row16;
        float v = acc[mi][ni][r] + bias;
        x2f[((size_t)b * 512 + o) * 2048 + t] = v;
        x2h[((size_t)b * 2048 + t) * 512 + o] = f2h(v);
      }
    }
}

// ---------------- K5: g/theta/phi projections
__global__ __launch_bounds__(256) void k_gtp(const _Float16* __restrict__ x2h,
                                             const _Float16* __restrict__ wth, const _Float16* __restrict__ wph,
                                             const _Float16* __restrict__ wg,
                                             const float* __restrict__ thb, const float* __restrict__ phb,
                                             const float* __restrict__ gb,
                                             _Float16* __restrict__ tht, _Float16* __restrict__ pht,
                                             _Float16* __restrict__ gv) {
  int b = blockIdx.z;
  int proj = blockIdx.y >> 1, dtile = blockIdx.y & 1;
  int wid = threadIdx.x >> 6, lane = threadIdx.x & 63;
  int wm = (wid >> 1) * 64, wn = (wid & 1) * 64;
  int row16 = lane & 15, kg = lane >> 4;
  const _Float16* X = x2h + (size_t)b * 2048 * 512;
  f4v acc[4][4];
#pragma unroll
  for (int mi = 0; mi < 4; ++mi)
#pragma unroll
    for (int ni = 0; ni < 4; ++ni) acc[mi][ni] = (f4v){0.f, 0.f, 0.f, 0.f};

  if (proj < 2) {
    // out[t][d] : A = x2h rows t, B = W rows d
    const _Float16* W = (proj == 0) ? wth : wph;
    const float* bias = (proj == 0) ? thb : phb;
    _Float16* out = (proj == 0) ? tht : pht;
    int m0 = blockIdx.x * 128, n0 = dtile * 128;
    gemm64x64(X + (size_t)(m0 + wm) * 512, 512, W + (size_t)(n0 + wn) * 512, 512, 512, lane, acc);
#pragma unroll
    for (int mi = 0; mi < 4; ++mi)
#pragma unroll
      for (int r = 0; r < 4; ++r) {
        int t = m0 + wm + mi * 16 + kg * 4 + r;
#pragma unroll
        for (int ni = 0; ni < 4; ++ni) {
          int d = n0 + wn + ni * 16 + row16;
          out[((size_t)b * 2048 + t) * 256 + d] = f2h(acc[mi][ni][r] + bias[d]);
        }
      }
  } else {
    // g: out[d][t] : A = W rows d, B = x2h rows t
    int m0 = dtile * 128, n0 = blockIdx.x * 128;
    gemm64x64(wg + (size_t)(m0 + wm) * 512, 512, X + (size_t)(n0 + wn) * 512, 512, 512, lane, acc);
#pragma unroll
    for (int mi = 0; mi < 4; ++mi)
#pragma unroll
      for (int r = 0; r < 4; ++r) {
        int d = m0 + wm + mi * 16 + kg * 4 + r;
        float bias = gb[d];
#pragma unroll
        for (int ni = 0; ni < 4; ++ni) {
          int t = n0 + wn + ni * 16 + row16;
          gv[((size_t)b * 256 + d) * 2048 + t] = f2h(acc[mi][ni][r] + bias);
        }
      }
  }
}

// ---------------- K6: flash attention, f16 MFMA. y[b][t][d] = softmax(th·ph^T)·g^T
__global__ __launch_bounds__(256) void k_attn(const _Float16* __restrict__ tht,
                                              const _Float16* __restrict__ pht,
                                              const _Float16* __restrict__ gv,
                                              _Float16* __restrict__ y) {
  int b = blockIdx.y;
  int wid = threadIdx.x >> 6, lane = threadIdx.x & 63;
  int q0 = blockIdx.x * 64 + wid * 16;
  int row16 = lane & 15, kg = lane >> 4, koff = kg * 8;
  __shared__ _Float16 p_lds[4][1024];  // per-wave 16x64 f16, XOR-swizzled
  char* pw = (char*)&p_lds[wid][0];
  const _Float16* thb = tht + (size_t)b * 2048 * 256;
  const _Float16* phb = pht + (size_t)b * 2048 * 256;
  const _Float16* gbp = gv + (size_t)b * 256 * 2048;

  h8v qf[8];
#pragma unroll
  for (int ks = 0; ks < 8; ++ks)
    qf[ks] = *(const h8v*)(thb + (size_t)(q0 + row16) * 256 + ks * 32 + koff);

  float m_i[4], l_i[4];
#pragma unroll
  for (int r = 0; r < 4; ++r) { m_i[r] = -3e38f; l_i[r] = 0.f; }
  f4v yacc[16];
#pragma unroll
  for (int ni = 0; ni < 16; ++ni) yacc[ni] = (f4v){0.f, 0.f, 0.f, 0.f};

  for (int kt = 0; kt < 32; ++kt) {
    int k0 = kt * 64;
    f4v sacc[4];
#pragma unroll
    for (int ni = 0; ni < 4; ++ni) sacc[ni] = (f4v){0.f, 0.f, 0.f, 0.f};
#pragma unroll
    for (int ks = 0; ks < 8; ++ks) {
#pragma unroll
      for (int ni = 0; ni < 4; ++ni) {
        h8v kf = *(const h8v*)(phb + (size_t)(k0 + ni * 16 + row16) * 256 + ks * 32 + koff);
        sacc[ni] = MFMA(qf[ks], kf, sacc[ni]);
      }
    }
    float al[4];
#pragma unroll
    for (int r = 0; r < 4; ++r) {
      float rm = fmaxf(fmaxf(sacc[0][r], sacc[1][r]), fmaxf(sacc[2][r], sacc[3][r]));
#pragma unroll
      for (int m = 1; m <= 8; m <<= 1) rm = fmaxf(rm, __shfl_xor(rm, m, 64));
      float mn = fmaxf(m_i[r], rm);
      al[r] = __expf(m_i[r] - mn);
      m_i[r] = mn;
      float rs = 0.f;
#pragma unroll
      for (int ni = 0; ni < 4; ++ni) {
        float p = __expf(sacc[ni][r] - mn);
        sacc[ni][r] = p;
        rs += p;
      }
#pragma unroll
      for (int m = 1; m <= 8; m <<= 1) rs += __shfl_xor(rs, m, 64);
      l_i[r] = l_i[r] * al[r] + rs;
    }
    // P -> LDS (f16, XOR-swizzled rows)
#pragma unroll
    for (int r = 0; r < 4; ++r) {
      int q = kg * 4 + r;
#pragma unroll
      for (int ni = 0; ni < 4; ++ni) {
        int sx = ni * 16 + row16;
        int byte = (q * 128 + sx * 2) ^ ((q & 7) << 4);
        *(_Float16*)(pw + byte) = f2h(sacc[ni][r]);
      }
    }
#pragma unroll
    for (int ni = 0; ni < 16; ++ni)
#pragma unroll
      for (int r = 0; r < 4; ++r) yacc[ni][r] *= al[r];
    // PV
#pragma unroll
    for (int ks2 = 0; ks2 < 2; ++ks2) {
      int byte = (row16 * 128 + (ks2 * 32 + koff) * 2) ^ ((row16 & 7) << 4);
      h8v pa = *(const h8v*)(pw + byte);
#pragma unroll
      for (int ni = 0; ni < 16; ++ni) {
        h8v vb = *(const h8v*)(gbp + (size_t)(ni * 16 + row16) * 2048 + k0 + ks2 * 32 + koff);
        yacc[ni] = MFMA(pa, vb, yacc[ni]);
      }
    }
  }
  _Float16* yb = y + (size_t)b * 2048 * 256;
#pragma unroll
  for (int r = 0; r < 4; ++r) {
    float inv = 1.f / l_i[r];
    int q = q0 + kg * 4 + r;
#pragma unroll
    for (int ni = 0; ni < 16; ++ni)
      yb[(size_t)q * 256 + ni * 16 + row16] = f2h(yacc[ni][r] * inv);
  }
}

// ---------------- K7: out = BN(W@y + Wb) + x2
__global__ __launch_bounds__(256) void k_final(const _Float16* __restrict__ Wh,
                                               const _Float16* __restrict__ yv,
                                               const float* __restrict__ Wb,
                                               const float* __restrict__ bng, const float* __restrict__ bnb,
                                               const float* __restrict__ bnm, const float* __restrict__ bnv,
                                               const float* __restrict__ x2f, float* __restrict__ out) {
  int b = blockIdx.z;
  int o0 = blockIdx.y * 128, t0 = blockIdx.x * 128;
  int wid = threadIdx.x >> 6, lane = threadIdx.x & 63;
  int wm = (wid >> 1) * 64, wn = (wid & 1) * 64;
  int row16 = lane & 15, kg = lane >> 4;
  f4v acc[4][4];
#pragma unroll
  for (int mi = 0; mi < 4; ++mi)
#pragma unroll
    for (int ni = 0; ni < 4; ++ni) acc[mi][ni] = (f4v){0.f, 0.f, 0.f, 0.f};
  gemm64x64(Wh + (size_t)(o0 + wm) * 256, 256,
            yv + (size_t)b * 2048 * 256 + (size_t)(t0 + wn) * 256, 256, 256, lane, acc);
#pragma unroll
  for (int mi = 0; mi < 4; ++mi)
#pragma unroll
    for (int r = 0; r < 4; ++r) {
      int o = o0 + wm + mi * 16 + kg * 4 + r;
      float sc = bng[o] * rsqrtf(bnv[o] + 1e-5f);
      float add = (Wb[o] - bnm[o]) * sc + bnb[o];
#pragma unroll
      for (int ni = 0; ni < 4; ++ni) {
        int t = t0 + wn + ni * 16 + row16;
        size_t idx = ((size_t)b * 512 + o) * 2048 + t;
        out[idx] = acc[mi][ni][r] * sc + add + x2f[idx];
      }
    }
}

extern "C" void kernel_launch(void* const* d_in, const int* in_sizes, int n_in,
                              void* d_out, int out_size, void* d_ws, size_t ws_size,
                              hipStream_t stream) {
  const float* x    = (const float*)d_in[0];
  const float* tcw1 = (const float*)d_in[1];
  const float* tcw2 = (const float*)d_in[2];
  const float* zw   = (const float*)d_in[3];
  const float* zb   = (const float*)d_in[4];
  const float* gw   = (const float*)d_in[5];
  const float* gb   = (const float*)d_in[6];
  const float* thw  = (const float*)d_in[7];
  const float* thb  = (const float*)d_in[8];
  const float* phw  = (const float*)d_in[9];
  const float* phb  = (const float*)d_in[10];
  const float* Ww   = (const float*)d_in[11];
  const float* Wb   = (const float*)d_in[12];
  const float* bng  = (const float*)d_in[13];
  const float* bnb  = (const float*)d_in[14];
  const float* bnm  = (const float*)d_in[15];
  const float* bnv  = (const float*)d_in[16];

  char* Wp = (char*)d_ws;
  _Float16* xpe = (_Float16*)(Wp);                  // [b][t][c] f16      16,777,216 B
  _Float16* Mh  = (_Float16*)(Wp + 16777216);       // [5][o][c] f16       2,621,440
  _Float16* x2h = (_Float16*)(Wp + 19398656);       // [b][t][c] f16      16,777,216
  float*    x2f = (float*)   (Wp + 36175872);       // [b][c][t] f32      33,554,432
  _Float16* tht = (_Float16*)(Wp + 69730304);       // [b][t][d] f16       8,388,608
  _Float16* pht = (_Float16*)(Wp + 78118912);       // [b][t][d] f16       8,388,608
  _Float16* gv  = (_Float16*)(Wp + 86507520);       // [b][d][t] f16       8,388,608
  _Float16* yv  = (_Float16*)(Wp + 94896128);       // [b][t][d] f16       8,388,608
  _Float16* wc  = (_Float16*)(Wp + 103284736);      // 4 x 131072 f16      1,048,576
  _Float16* wth = wc, *wph = wc + 131072, *wg = wc + 262144, *wW = wc + 393216;

  k_pe_t <<<dim3(64, 16, 8), 256, 0, stream>>>(x, xpe);
  k_cast <<<dim3(512, 4), 256, 0, stream>>>(thw, phw, gw, Ww, wc);
  k_merge<<<dim3(4, 4, 5), dim3(16, 16), 0, stream>>>(zw, tcw1, tcw2, Mh);
  k_conv <<<dim3(16, 4, 8), 256, 0, stream>>>(Mh, xpe, zb, x2f, x2h);
  k_gtp  <<<dim3(16, 6, 8), 256, 0, stream>>>(x2h, wth, wph, wg, thb, phb, gb, tht, pht, gv);
  k_attn <<<dim3(32, 8), 256, 0, stream>>>(tht, pht, gv, yv);
  k_final<<<dim3(16, 4, 8), 256, 0, stream>>>(wW, yv, Wb, bng, bnb, bnm, bnv, x2f, (float*)d_out);
}

// Round 4
// 595.439 us; speedup vs baseline: 4.6123x; 1.6083x over previous
//
#include <hip/hip_runtime.h>
#include <stdint.h>

typedef _Float16 h8v __attribute__((ext_vector_type(8)));
typedef float f4v __attribute__((ext_vector_type(4)));

#define MFMA(a,b,c) __builtin_amdgcn_mfma_f32_16x16x32_f16((a),(b),(c),0,0,0)

__device__ __forceinline__ _Float16 f2h(float f) { return (_Float16)f; }

// ---------------- K1: PE add + transpose:  xpe_t[b][t][c] = f16(x[b][c][t] + pe(t,c))
__global__ __launch_bounds__(256) void k_pe_t(const float* __restrict__ x, _Float16* __restrict__ xpe) {
  __shared__ float tile[32][33];
  int b = blockIdx.z;
  int t0 = blockIdx.x * 32, c0 = blockIdx.y * 32;
  int tid = threadIdx.x;
  int col = tid & 31, rowq = tid >> 5;
#pragma unroll
  for (int i = 0; i < 4; ++i) {
    int c = c0 + rowq + i * 8;
    int t = t0 + col;
    int j2 = c & ~1;
    float dv = expf(-0.01798894603885192f * (float)j2);  // ln(1e4)/512
    float ang = (float)t * dv;
    float pe = (c & 1) ? cosf(ang) : sinf(ang);
    tile[rowq + i * 8][col] = x[((size_t)b * 512 + c) * 2048 + t] + pe;
  }
  __syncthreads();
#pragma unroll
  for (int i = 0; i < 4; ++i) {
    int t = t0 + rowq + i * 8;
    int c = c0 + col;
    xpe[((size_t)b * 2048 + t) * 512 + c] = f2h(tile[col][rowq + i * 8]);
  }
}

// ---------------- K2a: cast projection weights to f16 (four 131072-elem arrays)
__global__ __launch_bounds__(256) void k_cast(const float* __restrict__ a0, const float* __restrict__ a1,
                                              const float* __restrict__ a2, const float* __restrict__ a3,
                                              _Float16* __restrict__ o) {
  int w = blockIdx.y;
  const float* s = (w == 0) ? a0 : (w == 1) ? a1 : (w == 2) ? a2 : a3;
  int i = blockIdx.x * 256 + threadIdx.x;
  o[(size_t)w * 131072 + i] = f2h(s[i]);
}

// ---------------- K2b: cast z_w (512x1536) to f16
__global__ __launch_bounds__(256) void k_castz(const float* __restrict__ zw, _Float16* __restrict__ zh) {
  int i = blockIdx.x * 256 + threadIdx.x;  // grid 3072 -> 786432
  zh[i] = f2h(zw[i]);
}

// ---------------- K2c: transpose-cast temporal conv weights
// src w[m][k*512+c] (512x1536 f32);  dst wt[z][c][m] f16, z = k (w1) or 3+k (w2)
__global__ __launch_bounds__(256) void k_wtrans(const float* __restrict__ w1, const float* __restrict__ w2,
                                                _Float16* __restrict__ wt) {
  int z = blockIdx.z;
  const float* src = (z < 3) ? w1 : w2;
  int k = (z < 3) ? z : z - 3;
  __shared__ _Float16 tile[64][65];
  int m0 = blockIdx.y * 64, c0 = blockIdx.x * 64;
  int tid = threadIdx.x;
  int tc = tid & 63, tm = tid >> 6;  // 4 rows per pass
#pragma unroll
  for (int i = 0; i < 16; ++i) {
    int m = m0 + tm + i * 4;
    tile[tm + i * 4][tc] = f2h(src[(size_t)m * 1536 + (size_t)k * 512 + c0 + tc]);
  }
  __syncthreads();
#pragma unroll
  for (int i = 0; i < 16; ++i) {
    int c = c0 + tm + i * 4;
    wt[((size_t)z * 512 + c) * 512 + m0 + tc] = tile[tc][tm + i * 4];
  }
}

// ---------------- K3: merge conv weights through z (f16 MFMA)
// M_s[o][c] = sum_m Zseg[o][m] * Wk[m][c];  A = zh rows o (stride 1536), B = wt rows c (stride 512)
__global__ __launch_bounds__(256) void k_merge(const _Float16* __restrict__ zh,
                                               const _Float16* __restrict__ wt,
                                               const float* __restrict__ zwf,
                                               _Float16* __restrict__ M) {
  int s = blockIdx.z;
  int wid = threadIdx.x >> 6, lane = threadIdx.x & 63;
  int o0 = blockIdx.y * 64 + (wid >> 1) * 32;
  int c0 = blockIdx.x * 64 + (wid & 1) * 32;
  int row16 = lane & 15, kg = lane >> 4, koff = kg * 8;
  f4v acc[2][2];
#pragma unroll
  for (int mi = 0; mi < 2; ++mi)
#pragma unroll
    for (int ni = 0; ni < 2; ++ni) acc[mi][ni] = (f4v){0.f, 0.f, 0.f, 0.f};

  int np = (s == 2) ? 2 : 1;
  for (int p = 0; p < np; ++p) {
    int seg, wi;
    if (s == 0)      { seg = 1024; wi = 3; }
    else if (s == 1) { seg = 512;  wi = 0; }
    else if (s == 3) { seg = 512;  wi = 2; }
    else if (s == 4) { seg = 1024; wi = 5; }
    else             { seg = (p == 0) ? 512 : 1024; wi = (p == 0) ? 1 : 4; }
    const _Float16* A = zh + seg;
    const _Float16* B = wt + (size_t)wi * 512 * 512;
    for (int k0 = 0; k0 < 512; k0 += 32) {
      h8v a[2], bv[2];
#pragma unroll
      for (int i = 0; i < 2; ++i)
        a[i] = *(const h8v*)(A + (size_t)(o0 + i * 16 + row16) * 1536 + k0 + koff);
#pragma unroll
      for (int i = 0; i < 2; ++i)
        bv[i] = *(const h8v*)(B + (size_t)(c0 + i * 16 + row16) * 512 + k0 + koff);
#pragma unroll
      for (int mi = 0; mi < 2; ++mi)
#pragma unroll
        for (int ni = 0; ni < 2; ++ni)
          acc[mi][ni] = MFMA(a[mi], bv[ni], acc[mi][ni]);
    }
  }
  _Float16* dst = M + (size_t)s * 512 * 512;
#pragma unroll
  for (int mi = 0; mi < 2; ++mi)
#pragma unroll
    for (int r = 0; r < 4; ++r) {
      int o = o0 + mi * 16 + kg * 4 + r;
#pragma unroll
      for (int ni = 0; ni < 2; ++ni) {
        int c = c0 + ni * 16 + row16;
        float v = acc[mi][ni][r];
        if (s == 2) v += zwf[(size_t)o * 1536 + c];
        dst[(size_t)o * 512 + c] = f2h(v);
      }
    }
}

// ---------------- shared 64x64-per-wave TN GEMM core (A[M][K], B[N][K], K-contig)
__device__ __forceinline__ void gemm64x64(const _Float16* __restrict__ A, int lda,
                                          const _Float16* __restrict__ B, int ldb,
                                          int K, int lane, f4v acc[4][4]) {
  const int row16 = lane & 15, koff = (lane >> 4) * 8;
  for (int k0 = 0; k0 < K; k0 += 32) {
    h8v a[4], bv[4];
#pragma unroll
    for (int i = 0; i < 4; ++i)
      a[i] = *(const h8v*)(A + (size_t)(i * 16 + row16) * lda + k0 + koff);
#pragma unroll
    for (int i = 0; i < 4; ++i)
      bv[i] = *(const h8v*)(B + (size_t)(i * 16 + row16) * ldb + k0 + koff);
#pragma unroll
    for (int mi = 0; mi < 4; ++mi)
#pragma unroll
      for (int ni = 0; ni < 4; ++ni)
        acc[mi][ni] = MFMA(a[mi], bv[ni], acc[mi][ni]);
  }
}

// ---------------- K4: conv GEMM  x2[o][t] = sum_s M_s[o][:]·xpe[t+s-2][:] + zb
__global__ __launch_bounds__(256) void k_conv(const _Float16* __restrict__ Mh,
                                              const _Float16* __restrict__ xpe,
                                              const float* __restrict__ zb,
                                              float* __restrict__ x2f,
                                              _Float16* __restrict__ x2h) {
  int b = blockIdx.z;
  int o0 = blockIdx.y * 128, t0 = blockIdx.x * 128;
  int wid = threadIdx.x >> 6, lane = threadIdx.x & 63;
  int wm = (wid >> 1) * 64, wn = (wid & 1) * 64;
  int row16 = lane & 15, kg = lane >> 4, koff = kg * 8;
  f4v acc[4][4];
#pragma unroll
  for (int mi = 0; mi < 4; ++mi)
#pragma unroll
    for (int ni = 0; ni < 4; ++ni) acc[mi][ni] = (f4v){0.f, 0.f, 0.f, 0.f};
  const _Float16* Xb = xpe + (size_t)b * 2048 * 512;
  const h8v zerov = {0, 0, 0, 0, 0, 0, 0, 0};

  for (int s = 0; s < 5; ++s) {
    const _Float16* A = Mh + (size_t)s * 512 * 512 + (size_t)(o0 + wm) * 512;
    int shift = s - 2;
    for (int k0 = 0; k0 < 512; k0 += 32) {
      h8v a[4], bv[4];
#pragma unroll
      for (int i = 0; i < 4; ++i)
        a[i] = *(const h8v*)(A + (size_t)(i * 16 + row16) * 512 + k0 + koff);
#pragma unroll
      for (int i = 0; i < 4; ++i) {
        int tr = t0 + wn + i * 16 + row16 + shift;
        bv[i] = (tr >= 0 && tr < 2048) ? *(const h8v*)(Xb + (size_t)tr * 512 + k0 + koff) : zerov;
      }
#pragma unroll
      for (int mi = 0; mi < 4; ++mi)
#pragma unroll
        for (int ni = 0; ni < 4; ++ni)
          acc[mi][ni] = MFMA(a[mi], bv[ni], acc[mi][ni]);
    }
  }
#pragma unroll
  for (int mi = 0; mi < 4; ++mi)
#pragma unroll
    for (int r = 0; r < 4; ++r) {
      int o = o0 + wm + mi * 16 + kg * 4 + r;
      float bias = zb[o];
#pragma unroll
      for (int ni = 0; ni < 4; ++ni) {
        int t = t0 + wn + ni * 16 + row16;
        float v = acc[mi][ni][r] + bias;
        x2f[((size_t)b * 512 + o) * 2048 + t] = v;
        x2h[((size_t)b * 2048 + t) * 512 + o] = f2h(v);
      }
    }
}

// ---------------- K5: g/theta/phi projections
__global__ __launch_bounds__(256) void k_gtp(const _Float16* __restrict__ x2h,
                                             const _Float16* __restrict__ wth, const _Float16* __restrict__ wph,
                                             const _Float16* __restrict__ wg,
                                             const float* __restrict__ thb, const float* __restrict__ phb,
                                             const float* __restrict__ gb,
                                             _Float16* __restrict__ tht, _Float16* __restrict__ pht,
                                             _Float16* __restrict__ gv) {
  int b = blockIdx.z;
  int proj = blockIdx.y >> 1, dtile = blockIdx.y & 1;
  int wid = threadIdx.x >> 6, lane = threadIdx.x & 63;
  int wm = (wid >> 1) * 64, wn = (wid & 1) * 64;
  int row16 = lane & 15, kg = lane >> 4;
  const _Float16* X = x2h + (size_t)b * 2048 * 512;
  f4v acc[4][4];
#pragma unroll
  for (int mi = 0; mi < 4; ++mi)
#pragma unroll
    for (int ni = 0; ni < 4; ++ni) acc[mi][ni] = (f4v){0.f, 0.f, 0.f, 0.f};

  if (proj < 2) {
    const _Float16* W = (proj == 0) ? wth : wph;
    const float* bias = (proj == 0) ? thb : phb;
    _Float16* out = (proj == 0) ? tht : pht;
    int m0 = blockIdx.x * 128, n0 = dtile * 128;
    gemm64x64(X + (size_t)(m0 + wm) * 512, 512, W + (size_t)(n0 + wn) * 512, 512, 512, lane, acc);
#pragma unroll
    for (int mi = 0; mi < 4; ++mi)
#pragma unroll
      for (int r = 0; r < 4; ++r) {
        int t = m0 + wm + mi * 16 + kg * 4 + r;
#pragma unroll
        for (int ni = 0; ni < 4; ++ni) {
          int d = n0 + wn + ni * 16 + row16;
          out[((size_t)b * 2048 + t) * 256 + d] = f2h(acc[mi][ni][r] + bias[d]);
        }
      }
  } else {
    int m0 = dtile * 128, n0 = blockIdx.x * 128;
    gemm64x64(wg + (size_t)(m0 + wm) * 512, 512, X + (size_t)(n0 + wn) * 512, 512, 512, lane, acc);
#pragma unroll
    for (int mi = 0; mi < 4; ++mi)
#pragma unroll
      for (int r = 0; r < 4; ++r) {
        int d = m0 + wm + mi * 16 + kg * 4 + r;
        float bias = gb[d];
#pragma unroll
        for (int ni = 0; ni < 4; ++ni) {
          int t = n0 + wn + ni * 16 + row16;
          gv[((size_t)b * 256 + d) * 2048 + t] = f2h(acc[mi][ni][r] + bias);
        }
      }
  }
}

// ---------------- K6: flash attention, f16 MFMA. y[b][t][d] = softmax(th·ph^T)·g^T
__global__ __launch_bounds__(256) void k_attn(const _Float16* __restrict__ tht,
                                              const _Float16* __restrict__ pht,
                                              const _Float16* __restrict__ gv,
                                              _Float16* __restrict__ y) {
  int b = blockIdx.y;
  int wid = threadIdx.x >> 6, lane = threadIdx.x & 63;
  int q0 = blockIdx.x * 64 + wid * 16;
  int row16 = lane & 15, kg = lane >> 4, koff = kg * 8;
  __shared__ _Float16 p_lds[4][1024];  // per-wave 16x64 f16, XOR-swizzled
  char* pw = (char*)&p_lds[wid][0];
  const _Float16* thb = tht + (size_t)b * 2048 * 256;
  const _Float16* phb = pht + (size_t)b * 2048 * 256;
  const _Float16* gbp = gv + (size_t)b * 256 * 2048;

  h8v qf[8];
#pragma unroll
  for (int ks = 0; ks < 8; ++ks)
    qf[ks] = *(const h8v*)(thb + (size_t)(q0 + row16) * 256 + ks * 32 + koff);

  float m_i[4], l_i[4];
#pragma unroll
  for (int r = 0; r < 4; ++r) { m_i[r] = -3e38f; l_i[r] = 0.f; }
  f4v yacc[16];
#pragma unroll
  for (int ni = 0; ni < 16; ++ni) yacc[ni] = (f4v){0.f, 0.f, 0.f, 0.f};

  for (int kt = 0; kt < 32; ++kt) {
    int k0 = kt * 64;
    f4v sacc[4];
#pragma unroll
    for (int ni = 0; ni < 4; ++ni) sacc[ni] = (f4v){0.f, 0.f, 0.f, 0.f};
#pragma unroll
    for (int ks = 0; ks < 8; ++ks) {
#pragma unroll
      for (int ni = 0; ni < 4; ++ni) {
        h8v kf = *(const h8v*)(phb + (size_t)(k0 + ni * 16 + row16) * 256 + ks * 32 + koff);
        sacc[ni] = MFMA(qf[ks], kf, sacc[ni]);
      }
    }
    float al[4];
#pragma unroll
    for (int r = 0; r < 4; ++r) {
      float rm = fmaxf(fmaxf(sacc[0][r], sacc[1][r]), fmaxf(sacc[2][r], sacc[3][r]));
#pragma unroll
      for (int m = 1; m <= 8; m <<= 1) rm = fmaxf(rm, __shfl_xor(rm, m, 64));
      float mn = fmaxf(m_i[r], rm);
      al[r] = __expf(m_i[r] - mn);
      m_i[r] = mn;
      float rs = 0.f;
#pragma unroll
      for (int ni = 0; ni < 4; ++ni) {
        float p = __expf(sacc[ni][r] - mn);
        sacc[ni][r] = p;
        rs += p;
      }
#pragma unroll
      for (int m = 1; m <= 8; m <<= 1) rs += __shfl_xor(rs, m, 64);
      l_i[r] = l_i[r] * al[r] + rs;
    }
    // P -> LDS (f16, XOR-swizzled rows)
#pragma unroll
    for (int r = 0; r < 4; ++r) {
      int q = kg * 4 + r;
#pragma unroll
      for (int ni = 0; ni < 4; ++ni) {
        int sx = ni * 16 + row16;
        int byte = (q * 128 + sx * 2) ^ ((q & 7) << 4);
        *(_Float16*)(pw + byte) = f2h(sacc[ni][r]);
      }
    }
#pragma unroll
    for (int ni = 0; ni < 16; ++ni)
#pragma unroll
      for (int r = 0; r < 4; ++r) yacc[ni][r] *= al[r];
    // PV
#pragma unroll
    for (int ks2 = 0; ks2 < 2; ++ks2) {
      int byte = (row16 * 128 + (ks2 * 32 + koff) * 2) ^ ((row16 & 7) << 4);
      h8v pa = *(const h8v*)(pw + byte);
#pragma unroll
      for (int ni = 0; ni < 16; ++ni) {
        h8v vb = *(const h8v*)(gbp + (size_t)(ni * 16 + row16) * 2048 + k0 + ks2 * 32 + koff);
        yacc[ni] = MFMA(pa, vb, yacc[ni]);
      }
    }
  }
  _Float16* yb = y + (size_t)b * 2048 * 256;
#pragma unroll
  for (int r = 0; r < 4; ++r) {
    float inv = 1.f / l_i[r];
    int q = q0 + kg * 4 + r;
#pragma unroll
    for (int ni = 0; ni < 16; ++ni)
      yb[(size_t)q * 256 + ni * 16 + row16] = f2h(yacc[ni][r] * inv);
  }
}

// ---------------- K7: out = BN(W@y + Wb) + x2
__global__ __launch_bounds__(256) void k_final(const _Float16* __restrict__ Wh,
                                               const _Float16* __restrict__ yv,
                                               const float* __restrict__ Wb,
                                               const float* __restrict__ bng, const float* __restrict__ bnb,
                                               const float* __restrict__ bnm, const float* __restrict__ bnv,
                                               const float* __restrict__ x2f, float* __restrict__ out) {
  int b = blockIdx.z;
  int o0 = blockIdx.y * 128, t0 = blockIdx.x * 128;
  int wid = threadIdx.x >> 6, lane = threadIdx.x & 63;
  int wm = (wid >> 1) * 64, wn = (wid & 1) * 64;
  int row16 = lane & 15, kg = lane >> 4;
  f4v acc[4][4];
#pragma unroll
  for (int mi = 0; mi < 4; ++mi)
#pragma unroll
    for (int ni = 0; ni < 4; ++ni) acc[mi][ni] = (f4v){0.f, 0.f, 0.f, 0.f};
  gemm64x64(Wh + (size_t)(o0 + wm) * 256, 256,
            yv + (size_t)b * 2048 * 256 + (size_t)(t0 + wn) * 256, 256, 256, lane, acc);
#pragma unroll
  for (int mi = 0; mi < 4; ++mi)
#pragma unroll
    for (int r = 0; r < 4; ++r) {
      int o = o0 + wm + mi * 16 + kg * 4 + r;
      float sc = bng[o] * rsqrtf(bnv[o] + 1e-5f);
      float add = (Wb[o] - bnm[o]) * sc + bnb[o];
#pragma unroll
      for (int ni = 0; ni < 4; ++ni) {
        int t = t0 + wn + ni * 16 + row16;
        size_t idx = ((size_t)b * 512 + o) * 2048 + t;
        out[idx] = acc[mi][ni][r] * sc + add + x2f[idx];
      }
    }
}

extern "C" void kernel_launch(void* const* d_in, const int* in_sizes, int n_in,
                              void* d_out, int out_size, void* d_ws, size_t ws_size,
                              hipStream_t stream) {
  const float* x    = (const float*)d_in[0];
  const float* tcw1 = (const float*)d_in[1];
  const float* tcw2 = (const float*)d_in[2];
  const float* zw   = (const float*)d_in[3];
  const float* zb   = (const float*)d_in[4];
  const float* gw   = (const float*)d_in[5];
  const float* gb   = (const float*)d_in[6];
  const float* thw  = (const float*)d_in[7];
  const float* thb  = (const float*)d_in[8];
  const float* phw  = (const float*)d_in[9];
  const float* phb  = (const float*)d_in[10];
  const float* Ww   = (const float*)d_in[11];
  const float* Wb   = (const float*)d_in[12];
  const float* bng  = (const float*)d_in[13];
  const float* bnb  = (const float*)d_in[14];
  const float* bnm  = (const float*)d_in[15];
  const float* bnv  = (const float*)d_in[16];

  char* Wp = (char*)d_ws;
  _Float16* xpe = (_Float16*)(Wp);                  // [b][t][c] f16      16,777,216 B
  _Float16* Mh  = (_Float16*)(Wp + 16777216);       // [5][o][c] f16       2,621,440
  _Float16* x2h = (_Float16*)(Wp + 19398656);       // [b][t][c] f16      16,777,216
  float*    x2f = (float*)   (Wp + 36175872);       // [b][c][t] f32      33,554,432
  _Float16* tht = (_Float16*)(Wp + 69730304);       // [b][t][d] f16       8,388,608
  _Float16* pht = (_Float16*)(Wp + 78118912);       // [b][t][d] f16       8,388,608
  _Float16* gv  = (_Float16*)(Wp + 86507520);       // [b][d][t] f16       8,388,608
  _Float16* yv  = (_Float16*)(Wp + 94896128);       // [b][t][d] f16       8,388,608
  _Float16* wc  = (_Float16*)(Wp + 103284736);      // 4 x 131072 f16      1,048,576
  _Float16* wth = wc, *wph = wc + 131072, *wg = wc + 262144, *wW = wc + 393216;
  // merge scratch aliases x2f region (dead until k_conv, which runs after k_merge)
  _Float16* zh  = (_Float16*)(Wp + 36175872);                // 512x1536 f16  1,572,864 B
  _Float16* wt  = (_Float16*)(Wp + 36175872 + 1572864);      // 6x512x512 f16 3,145,728 B

  k_cast  <<<dim3(512, 4), 256, 0, stream>>>(thw, phw, gw, Ww, wc);
  k_castz <<<3072, 256, 0, stream>>>(zw, zh);
  k_wtrans<<<dim3(8, 8, 6), 256, 0, stream>>>(tcw1, tcw2, wt);
  k_merge <<<dim3(8, 8, 5), 256, 0, stream>>>(zh, wt, zw, Mh);
  k_pe_t  <<<dim3(64, 16, 8), 256, 0, stream>>>(x, xpe);
  k_conv  <<<dim3(16, 4, 8), 256, 0, stream>>>(Mh, xpe, zb, x2f, x2h);
  k_gtp   <<<dim3(16, 6, 8), 256, 0, stream>>>(x2h, wth, wph, wg, thb, phb, gb, tht, pht, gv);
  k_attn  <<<dim3(32, 8), 256, 0, stream>>>(tht, pht, gv, yv);
  k_final <<<dim3(16, 4, 8), 256, 0, stream>>>(wW, yv, Wb, bng, bnb, bnm, bnv, x2f, (float*)d_out);
}